// Round 1
// baseline (164.255 us; speedup 1.0000x reference)
//
#include <hip/hip_runtime.h>

#define VOLUME 128
#define K_OFF 125          // (2*R_OFF+1)^3
#define B_ 4
#define N_ 4096
#define NVOX (B_ * VOLUME * VOLUME * VOLUME)   // 8,388,608
#define ORD_NEG_INF 0x807fffff   // f2o(-inf)
#define ORD_POS_INF 0x7f800000   // f2o(+inf)

// Monotone bijection float <-> int preserving order (no NaNs in this problem).
__device__ __forceinline__ int f2o(float f) {
    int i = __float_as_int(f);
    return i >= 0 ? i : i ^ 0x7fffffff;
}
__device__ __forceinline__ float o2f(int i) {
    return __int_as_float(i >= 0 ? i : i ^ 0x7fffffff);
}

// Pass 1: init accumulators. out channels: [0]=ord(-inf) (max), [1]=ord(+inf) (min),
// [2]=0.0f (sum). cnt zeroed. Fully coalesced: one element per thread.
__global__ void vdw_init(int* __restrict__ out_i, unsigned int* __restrict__ cnt,
                         int n3, int nvox) {
    int i = blockIdx.x * blockDim.x + threadIdx.x;
    if (i < n3) {
        int c = i - (i / 3) * 3;
        out_i[i] = (c == 0) ? ORD_NEG_INF : (c == 1) ? ORD_POS_INF : 0;
    }
    if (i < nvox) cnt[i] = 0u;
}

// Pass 2: one thread per (point, offset-k). k in [0,125).
__global__ void vdw_scatter(const float4* __restrict__ cr,
                            const float* __restrict__ feat,
                            int* __restrict__ out_i,
                            float* __restrict__ out_f,
                            unsigned int* __restrict__ cnt) {
    int t = blockIdx.x * blockDim.x + threadIdx.x;
    const int total = B_ * N_ * K_OFF;
    if (t >= total) return;
    int point = t / K_OFF;
    int k = t - point * K_OFF;

    float4 c = cr[point];  // x,y,z,radius — 125 threads share; L1/L2 broadcast

    // offsets via meshgrid 'ij' ravel: ox slowest, oz fastest
    int ox = k / 25;
    int rem = k - ox * 25;
    int oy = rem / 5;
    int oz = rem - oy * 5;

    // round-half-even to match jnp.round
    int vx = __float2int_rn(c.x) + ox - 2;
    int vy = __float2int_rn(c.y) + oy - 2;
    int vz = __float2int_rn(c.z) + oz - 2;

    // strict IEEE fp32, no FMA contraction, to match the numpy reference
    float dx = __fsub_rn((float)vx, c.x);
    float dy = __fsub_rn((float)vy, c.y);
    float dz = __fsub_rn((float)vz, c.z);
    float dist2 = __fadd_rn(__fadd_rn(__fmul_rn(dx, dx), __fmul_rn(dy, dy)),
                            __fmul_rn(dz, dz));
    float r = __fdiv_rn(rintf(__fmul_rn(c.w, 1000.0f)), 1000.0f);
    float r2 = __fmul_rn(r, r);

    bool inb = ((unsigned)vx < (unsigned)VOLUME) &&
               ((unsigned)vy < (unsigned)VOLUME) &&
               ((unsigned)vz < (unsigned)VOLUME);
    if (inb && dist2 <= r2) {
        int b = point >> 12;  // N_ = 4096
        int lin = ((vx * VOLUME + vy) * VOLUME + vz) + b * (VOLUME * VOLUME * VOLUME);
        float f0 = feat[point * 3 + 0];
        float f1 = feat[point * 3 + 1];
        float f2 = feat[point * 3 + 2];
        atomicMax(&out_i[lin * 3 + 0], f2o(f0));
        atomicMin(&out_i[lin * 3 + 1], f2o(f1));
        atomicAdd(&out_f[lin * 3 + 2], f2);
        atomicAdd(&cnt[lin], 1u);
    }
}

// Pass 3: finalize in place.
__global__ void vdw_finalize(int* __restrict__ out_i, float* __restrict__ out_f,
                             const unsigned int* __restrict__ cnt, int nvox) {
    int i = blockIdx.x * blockDim.x + threadIdx.x;
    if (i >= nvox) return;
    unsigned int c = cnt[i];
    int mo = out_i[3 * i + 0];
    int no = out_i[3 * i + 1];
    float s = out_f[3 * i + 2];
    float o0 = 0.0f, o1 = 0.0f, o2 = 0.0f;
    if (c > 0u) {
        o0 = o2f(mo);
        o1 = o2f(no);
        o2 = __fdiv_rn(s, (float)c);
    }
    out_f[3 * i + 0] = o0;
    out_f[3 * i + 1] = o1;
    out_f[3 * i + 2] = o2;
}

extern "C" void kernel_launch(void* const* d_in, const int* in_sizes, int n_in,
                              void* d_out, int out_size, void* d_ws, size_t ws_size,
                              hipStream_t stream) {
    const float4* cr = (const float4*)d_in[0];       // (B,N,4) fp32
    const float* feat = (const float*)d_in[1];       // (B,N,3) fp32
    float* out = (float*)d_out;                      // (B,V,V,V,3) fp32
    unsigned int* cnt = (unsigned int*)d_ws;         // NVOX uints = 33.5 MB

    const int nvox = NVOX;
    const int n3 = nvox * 3;                         // == out_size
    const int nscatter = B_ * N_ * K_OFF;

    vdw_init<<<(n3 + 255) / 256, 256, 0, stream>>>((int*)out, cnt, n3, nvox);
    vdw_scatter<<<(nscatter + 255) / 256, 256, 0, stream>>>(cr, feat, (int*)out, out, cnt);
    vdw_finalize<<<(nvox + 255) / 256, 256, 0, stream>>>((int*)out, out, cnt, nvox);
}